// Round 1
// baseline (317.442 us; speedup 1.0000x reference)
//
#include <hip/hip_runtime.h>
#include <hip/hip_bf16.h>

#define BATCH 16
#define NCAND 25200
#define NCLS 80
#define PREDC 85
#define KTOP 1000
#define MAXDET 300
#define CAP 2048
#define NBINS 1024
#define TILE_ROWS 128

// ---------------- K1: per-candidate score ----------------
__global__ __launch_bounds__(TILE_ROWS) void k_score(const float* __restrict__ pred,
                                                     float* __restrict__ score) {
    __shared__ float lds[TILE_ROWS * PREDC];
    int tile = blockIdx.x;
    int tid = threadIdx.x;
    size_t base = (size_t)tile * (TILE_ROWS * PREDC);
    const float4* src4 = (const float4*)(pred + base);
    float4* l4 = (float4*)lds;
    const int NV4 = TILE_ROWS * PREDC / 4;  // 2720
    for (int k = tid; k < NV4; k += TILE_ROWS) l4[k] = src4[k];
    __syncthreads();
    const float* row = lds + tid * PREDC;
    float obj = row[4];
    float best = -1.0f;
    #pragma unroll 8
    for (int c = 0; c < NCLS; ++c) {
        float v = row[5 + c] * obj;
        if (v > best) best = v;
    }
    bool valid = (obj > 0.45f) && (best > 0.45f);
    score[(size_t)tile * TILE_ROWS + tid] = valid ? best : -1.0f;
}

// ---------------- K2: per-image top-K + gather ----------------
__global__ __launch_bounds__(256) void k_topk(const float* __restrict__ pred,
                                              const float* __restrict__ score,
                                              int* __restrict__ topidx,
                                              float* __restrict__ topsc,
                                              int* __restrict__ topcls,
                                              float* __restrict__ boxes,
                                              int* __restrict__ cntarr,
                                              unsigned long long* __restrict__ nzw) {
    int b = blockIdx.x, tid = threadIdx.x;
    __shared__ int hist[NBINS];
    __shared__ unsigned long long sbuf[CAP];
    __shared__ int s_cnt, s_T;
    const float CONF = 0.45f;
    const float SCALE = (float)NBINS / (1.0f - 0.45f);
    for (int i = tid; i < NBINS; i += 256) hist[i] = 0;
    if (tid == 0) { s_cnt = 0; s_T = 0; }
    if (tid < 16) nzw[b * 16 + tid] = 0ULL;  // zero for K3's atomicOr
    __syncthreads();
    const float* sc = score + (size_t)b * NCAND;
    for (int n = tid; n < NCAND; n += 256) {
        float s = sc[n];
        if (s > CONF) {
            int bin = (int)((s - CONF) * SCALE);
            bin = bin < 0 ? 0 : (bin > NBINS - 1 ? NBINS - 1 : bin);
            atomicAdd(&hist[bin], 1);
        }
    }
    __syncthreads();
    // suffix sum (Hillis-Steele)
    for (int off = 1; off < NBINS; off <<= 1) {
        int tmp[4];
        #pragma unroll
        for (int k = 0; k < 4; ++k) {
            int idx = tid + k * 256;
            tmp[k] = (idx + off < NBINS) ? hist[idx + off] : 0;
        }
        __syncthreads();
        #pragma unroll
        for (int k = 0; k < 4; ++k) hist[tid + k * 256] += tmp[k];
        __syncthreads();
    }
    // find threshold bin T = max t with S(t) >= KTOP
    #pragma unroll
    for (int k = 0; k < 4; ++k) {
        int idx = tid + k * 256;
        int S = hist[idx];
        int Sn = (idx + 1 < NBINS) ? hist[idx + 1] : 0;
        if (S >= KTOP && Sn < KTOP) s_T = idx;
    }
    __syncthreads();
    int T = s_T;
    for (int i = tid; i < CAP; i += 256) sbuf[i] = ~0ULL;
    __syncthreads();
    for (int n = tid; n < NCAND; n += 256) {
        float s = sc[n];
        if (s > CONF) {
            int bin = (int)((s - CONF) * SCALE);
            bin = bin < 0 ? 0 : (bin > NBINS - 1 ? NBINS - 1 : bin);
            if (bin >= T) {
                int pos = atomicAdd(&s_cnt, 1);
                if (pos < CAP) {
                    unsigned int sb = __float_as_uint(s);
                    sbuf[pos] = ((unsigned long long)(~sb) << 32) | (unsigned)n;
                }
            }
        }
    }
    __syncthreads();
    int C2 = s_cnt; if (C2 > CAP) C2 = CAP;
    // bitonic sort ascending: key = (~score_bits, idx) -> score desc, idx asc
    for (unsigned k = 2; k <= CAP; k <<= 1) {
        for (unsigned j = k >> 1; j > 0; j >>= 1) {
            __syncthreads();
            for (unsigned t = tid; t < CAP; t += 256) {
                unsigned ixj = t ^ j;
                if (ixj > t) {
                    unsigned long long a = sbuf[t], bb = sbuf[ixj];
                    if ((a > bb) == ((t & k) == 0)) { sbuf[t] = bb; sbuf[ixj] = a; }
                }
            }
        }
    }
    __syncthreads();
    for (int r = tid; r < KTOP; r += 256) {
        int o = b * KTOP + r;
        if (r < C2) {
            unsigned long long key = sbuf[r];
            int n = (int)(key & 0xFFFFFFFFULL);
            float s = __uint_as_float(~(unsigned int)(key >> 32));
            const float* row = pred + ((size_t)b * NCAND + n) * PREDC;
            float cx = row[0], cy = row[1], w = row[2], h = row[3];
            float obj = row[4];
            float best = -1.0f; int bj = 0;
            for (int c = 0; c < NCLS; ++c) {
                float v = row[5 + c] * obj;
                if (v > best) { best = v; bj = c; }
            }
            topidx[o] = n; topsc[o] = s; topcls[o] = bj;
            ((float4*)boxes)[o] = make_float4(cx - w * 0.5f, cy - h * 0.5f,
                                              cx + w * 0.5f, cy + h * 0.5f);
        } else {
            topidx[o] = 0; topsc[o] = -1.0f; topcls[o] = 0;
            ((float4*)boxes)[o] = make_float4(0.f, 0.f, 0.f, 0.f);
        }
    }
    if (tid == 0) cntarr[b] = C2 < KTOP ? C2 : KTOP;
}

// ---------------- K3: IoU bitmask (j>i, iou>thr) + nz bitmap ----------------
__global__ __launch_bounds__(256) void k_iou(const float* __restrict__ boxes,
                                             unsigned long long* __restrict__ M,
                                             unsigned long long* __restrict__ nzw) {
    #pragma clang fp contract(off)
    int g = blockIdx.x * 256 + threadIdx.x;   // 16*1000*16 = 256000
    int w = g & 15;
    int bi = g >> 4;                          // 0..15999
    int i = bi % KTOP;
    int b = bi / KTOP;
    const float4* bx = (const float4*)boxes + (size_t)b * KTOP;
    float4 A = bx[i];
    float areaA = (A.z - A.x) * (A.w - A.y);
    unsigned long long word = 0;
    int j0 = w * 64;
    int jend = j0 + 64; if (jend > KTOP) jend = KTOP;
    #pragma unroll 4
    for (int j = j0; j < jend; ++j) {
        float4 Bb = bx[j];
        float areaB = (Bb.z - Bb.x) * (Bb.w - Bb.y);
        float lx = fmaxf(A.x, Bb.x), ly = fmaxf(A.y, Bb.y);
        float rx = fminf(A.z, Bb.z), ry = fminf(A.w, Bb.w);
        float ww = rx - lx; ww = ww > 0.f ? ww : 0.f;
        float hh = ry - ly; hh = hh > 0.f ? hh : 0.f;
        float inter = ww * hh;
        float denom = ((areaA + areaB) - inter) + 1e-9f;
        float iou = inter / denom;
        if (j > i && iou > 0.45f) word |= 1ULL << (j - j0);
    }
    M[(size_t)bi * 16 + w] = word;
    if (word) atomicOr(&nzw[b * 16 + (i >> 6)], 1ULL << (i & 63));
}

// ---------------- K4: sequential greedy NMS over nz rows ----------------
__global__ __launch_bounds__(64) void k_nms(const unsigned long long* __restrict__ M,
                                            const unsigned long long* __restrict__ nzw,
                                            const int* __restrict__ cntarr,
                                            unsigned long long* __restrict__ keepw) {
    int b = blockIdx.x, l = threadIdx.x;
    __shared__ unsigned long long s_nzw[16];
    __shared__ int nzlist[1024];
    __shared__ int s_nnz;
    if (l < 16) s_nzw[l] = nzw[b * 16 + l];
    __syncthreads();
    if (l < 16) {
        int pre = 0;
        for (int u = 0; u < l; ++u) pre += __popcll(s_nzw[u]);
        unsigned long long wv = s_nzw[l];
        int ofs = pre;
        while (wv) {
            int bit = __builtin_ctzll(wv);
            nzlist[ofs++] = l * 64 + bit;
            wv &= wv - 1;
        }
        if (l == 15) s_nnz = ofs;
    }
    __syncthreads();
    int nnz = s_nnz;
    int kc0 = cntarr[b];
    int w = l & 15;
    // supp init: bits >= kc0 suppressed
    int lo = w * 64;
    unsigned long long supp;
    if (kc0 <= lo) supp = ~0ULL;
    else if (kc0 >= lo + 64) supp = 0ULL;
    else supp = (~0ULL) << (kc0 - lo);
    const unsigned long long* Mb = M + (size_t)b * KTOP * 16;
    int i_next = 0; unsigned long long w_next = 0;
    if (nnz > 0) { i_next = nzlist[0]; w_next = Mb[(size_t)i_next * 16 + w]; }
    for (int k = 0; k < nnz; ++k) {
        int i = i_next;
        unsigned long long mw = w_next;
        if (k + 1 < nnz) { i_next = nzlist[k + 1]; w_next = Mb[(size_t)i_next * 16 + w]; }
        int src = i >> 6;
        int slo = __shfl((int)(supp & 0xFFFFFFFFULL), src);
        int shi = __shfl((int)(supp >> 32), src);
        unsigned long long sw = ((unsigned long long)(unsigned)shi << 32) | (unsigned)slo;
        bool alive = ((sw >> (i & 63)) & 1ULL) == 0ULL;
        if (alive) supp |= mw;   // wave-uniform condition
    }
    if (l < 16) keepw[b * 16 + l] = ~supp;
}

// ---------------- K5: compact keep -> top-300 outputs ----------------
__global__ __launch_bounds__(256) void k_out(const float* __restrict__ logits,
                                             const unsigned long long* __restrict__ keepw,
                                             const int* __restrict__ topidx,
                                             const float* __restrict__ topsc,
                                             const int* __restrict__ topcls,
                                             const float* __restrict__ boxes,
                                             float* __restrict__ out) {
    int b = blockIdx.x, tid = threadIdx.x;
    __shared__ int kept_r[MAXDET];
    __shared__ int kept_n[MAXDET];
    __shared__ int s_kc;
    __shared__ unsigned long long s_kw[16];
    if (tid < 16) s_kw[tid] = keepw[b * 16 + tid];
    __syncthreads();
    if (tid < 16) {
        int pre = 0;
        for (int u = 0; u < tid; ++u) pre += __popcll(s_kw[u]);
        unsigned long long wv = s_kw[tid];
        int rank = pre;
        while (wv) {
            int bit = __builtin_ctzll(wv);
            if (rank < MAXDET) kept_r[rank] = tid * 64 + bit;
            rank++;
            wv &= wv - 1;
        }
        if (tid == 15) s_kc = rank < MAXDET ? rank : MAXDET;
    }
    __syncthreads();
    int kc = s_kc;
    for (int s = tid; s < MAXDET; s += 256)
        if (s < kc) kept_n[s] = topidx[b * KTOP + kept_r[s]];
    __syncthreads();
    float* det = out;                                        // [16][300][6]
    float* maskо = out + BATCH * MAXDET * 6;                 // [16][300]
    float* lgo = out + BATCH * MAXDET * 6 + BATCH * MAXDET;  // [16][300][80]
    for (int idx = tid; idx < MAXDET * 6; idx += 256) {
        int s = idx / 6, col = idx % 6;
        float v = 0.f;
        if (s < kc) {
            int o = b * KTOP + kept_r[s];
            if (col < 4) v = boxes[o * 4 + col];
            else if (col == 4) v = topsc[o];
            else v = (float)topcls[o];
        }
        det[b * MAXDET * 6 + idx] = v;
    }
    for (int s = tid; s < MAXDET; s += 256)
        maskо[b * MAXDET + s] = (s < kc) ? 1.0f : 0.0f;
    for (int idx = tid; idx < MAXDET * NCLS; idx += 256) {
        int s = idx / NCLS, c = idx % NCLS;
        float v = 0.f;
        if (s < kc) v = logits[((size_t)b * NCAND + kept_n[s]) * NCLS + c];
        lgo[b * MAXDET * NCLS + idx] = v;
    }
}

extern "C" void kernel_launch(void* const* d_in, const int* in_sizes, int n_in,
                              void* d_out, int out_size, void* d_ws, size_t ws_size,
                              hipStream_t stream) {
    (void)in_sizes; (void)n_in; (void)out_size; (void)ws_size;
    const float* pred = (const float*)d_in[0];
    const float* logits = (const float*)d_in[1];
    float* out = (float*)d_out;
    char* ws = (char*)d_ws;

    // workspace layout (bytes)
    float* score  = (float*)(ws + 0);                          // 16*25200*4 = 1,612,800
    int*   topidx = (int*)(ws + 1612800);                      // 64,000
    float* topsc  = (float*)(ws + 1676800);                    // 64,000
    int*   topcls = (int*)(ws + 1740800);                      // 64,000
    float* boxes  = (float*)(ws + 1804800);                    // 256,000 (16B aligned)
    unsigned long long* M    = (unsigned long long*)(ws + 2060800);  // 2,048,000
    unsigned long long* nzw  = (unsigned long long*)(ws + 4108800);  // 2,048
    int*   cntarr = (int*)(ws + 4110848);                      // 256
    unsigned long long* keepw = (unsigned long long*)(ws + 4111104); // 2,048

    const int nrows = BATCH * NCAND;                 // 403200
    k_score<<<nrows / TILE_ROWS, TILE_ROWS, 0, stream>>>(pred, score);
    k_topk<<<BATCH, 256, 0, stream>>>(pred, score, topidx, topsc, topcls, boxes, cntarr, nzw);
    k_iou<<<(BATCH * KTOP * 16) / 256, 256, 0, stream>>>(boxes, M, nzw);
    k_nms<<<BATCH, 64, 0, stream>>>(M, nzw, cntarr, keepw);
    k_out<<<BATCH, 256, 0, stream>>>(logits, keepw, topidx, topsc, topcls, boxes, out);
}